// Round 2
// baseline (5218.711 us; speedup 1.0000x reference)
//
#include <hip/hip_runtime.h>
#include <hip/hip_bf16.h>

// ---------------- constants ----------------
#define Bb    8
#define IMG   224
#define Hp    14
#define Np    196      // tokens per image
#define D4    128
#define D8    256
#define EMB   512
#define HEADS 8
#define HD    64
#define RPEL  729
#define DEPTH 24
#define EPS   1e-5f

constexpr int EPI_NONE = 0, EPI_BIAS = 1, EPI_BIAS_GELU = 2, EPI_BIAS_RES = 3;

typedef __bf16 bf16x8 __attribute__((ext_vector_type(8)));
typedef float  f32x4  __attribute__((ext_vector_type(4)));

static __device__ __forceinline__ __bf16 bf_from_bits(unsigned int v) {
    union { unsigned short u; __bf16 b; } c; c.u = (unsigned short)v; return c.b;
}
static __device__ __forceinline__ unsigned int pack_bf2(float lo, float hi) {
    union { __bf16 b; unsigned short u; } a, c;
    a.b = (__bf16)lo; c.b = (__bf16)hi;
    return (unsigned int)a.u | ((unsigned int)c.u << 16);
}

// ================= conv 4x4/4 + patchify + per-pixel LN =================
// one block (128 threads) per output pixel (b, h', w'); writes X[bn][inner][128] (f32)
__global__ __launch_bounds__(128) void conv_ln_kernel(
    const float* __restrict__ img, const float* __restrict__ cw,
    const float* __restrict__ cb,  const float* __restrict__ png,
    const float* __restrict__ pnb, float* __restrict__ xout)
{
    int p = blockIdx.x;                 // b*3136 + h'*56 + w'
    int b = p / 3136, rem = p % 3136;
    int hh = rem / 56, ww = rem % 56;
    __shared__ float win[48];
    __shared__ float red[4];
    int t = threadIdx.x;
    if (t < 48) {
        int ic = t >> 4, kh = (t >> 2) & 3, kw = t & 3;
        win[t] = img[(((size_t)b*3 + ic)*224 + hh*4 + kh)*224 + ww*4 + kw];
    }
    __syncthreads();
    float acc = cb[t];
    const float* wrow = cw + (size_t)t * 48;
    #pragma unroll
    for (int r = 0; r < 48; ++r) acc += win[r] * wrow[r];
    // LN over the 128 channels (= 128 threads)
    float s = acc, ss = acc * acc;
    #pragma unroll
    for (int o = 32; o > 0; o >>= 1) { s += __shfl_xor(s, o, 64); ss += __shfl_xor(ss, o, 64); }
    int wv = t >> 6;
    if ((t & 63) == 0) { red[wv*2] = s; red[wv*2+1] = ss; }
    __syncthreads();
    s = red[0] + red[2]; ss = red[1] + red[3];
    float mean = s * (1.f/128.f);
    float rstd = rsqrtf(ss * (1.f/128.f) - mean*mean + EPS);
    float v = (acc - mean) * rstd * png[t] + pnb[t];
    int hp = hh >> 2, ih = hh & 3, wp = ww >> 2, iw = ww & 3;
    int bn = b * Np + hp * Hp + wp;
    xout[((size_t)bn*16 + ih*4 + iw)*128 + t] = v;
}

// ================= generic LayerNorm: one wave per row, f32 in -> bf16 out =================
__global__ __launch_bounds__(256) void ln_kernel(
    const float* __restrict__ x, const float* __restrict__ g,
    const float* __restrict__ b, __bf16* __restrict__ y, int M, int D)
{
    int wave = threadIdx.x >> 6, lane = threadIdx.x & 63;
    int row = blockIdx.x * 4 + wave;
    if (row >= M) return;
    const float* xr = x + (size_t)row * D;
    float s = 0.f, ss = 0.f;
    for (int i = lane; i < D; i += 64) { float v = xr[i]; s += v; ss += v*v; }
    #pragma unroll
    for (int o = 32; o > 0; o >>= 1) { s += __shfl_xor(s, o, 64); ss += __shfl_xor(ss, o, 64); }
    float inv = 1.f / (float)D;
    float mean = s * inv;
    float rstd = rsqrtf(ss * inv - mean*mean + EPS);
    __bf16* yr = y + (size_t)row * D;
    for (int i = lane; i < D; i += 64)
        yr[i] = (__bf16)((xr[i] - mean) * rstd * g[i] + b[i]);
}

// ================= merge1: gather 2x2 inner (dim128->512) + LN =================
// x: [1568*16, 128] f32  ->  y: [6272, 512] bf16
__global__ __launch_bounds__(256) void merge1_ln_kernel(
    const float* __restrict__ x, const float* __restrict__ g,
    const float* __restrict__ b, __bf16* __restrict__ y)
{
    int wave = threadIdx.x >> 6, lane = threadIdx.x & 63;
    int row = blockIdx.x * 4 + wave;
    if (row >= 6272) return;
    int j2 = row & 1, i2 = (row >> 1) & 1, bn = row >> 2;
    float vals[8]; float s = 0.f, ss = 0.f;
    #pragma unroll
    for (int t = 0; t < 8; ++t) {
        int e = lane + t*64;
        int k = e >> 7, c = e & 127;
        int ih = 2*i2 + (k & 1), iw = 2*j2 + (k >> 1);
        float v = x[((size_t)bn*16 + ih*4 + iw)*128 + c];
        vals[t] = v; s += v; ss += v*v;
    }
    #pragma unroll
    for (int o = 32; o > 0; o >>= 1) { s += __shfl_xor(s, o, 64); ss += __shfl_xor(ss, o, 64); }
    float mean = s * (1.f/512.f);
    float rstd = rsqrtf(ss * (1.f/512.f) - mean*mean + EPS);
    __bf16* yr = y + (size_t)row * 512;
    #pragma unroll
    for (int t = 0; t < 8; ++t) {
        int e = lane + t*64;
        yr[e] = (__bf16)((vals[t] - mean) * rstd * g[e] + b[e]);
    }
}

// ================= merge2: gather 2x2 tokens (dim256->1024) + LN =================
// x: [6272, 256] f32 (rows = bn*4 + ih*2 + iw) -> y: [1568, 1024] bf16
__global__ __launch_bounds__(256) void merge2_ln_kernel(
    const float* __restrict__ x, const float* __restrict__ g,
    const float* __restrict__ b, __bf16* __restrict__ y)
{
    int wave = threadIdx.x >> 6, lane = threadIdx.x & 63;
    int row = blockIdx.x * 4 + wave;
    if (row >= 1568) return;
    float vals[16]; float s = 0.f, ss = 0.f;
    #pragma unroll
    for (int t = 0; t < 16; ++t) {
        int e = lane + t*64;
        int k = e >> 8, c = e & 255;
        float v = x[((size_t)row*4 + (k & 1)*2 + (k >> 1))*256 + c];
        vals[t] = v; s += v; ss += v*v;
    }
    #pragma unroll
    for (int o = 32; o > 0; o >>= 1) { s += __shfl_xor(s, o, 64); ss += __shfl_xor(ss, o, 64); }
    float mean = s * (1.f/1024.f);
    float rstd = rsqrtf(ss * (1.f/1024.f) - mean*mean + EPS);
    __bf16* yr = y + (size_t)row * 1024;
    #pragma unroll
    for (int t = 0; t < 16; ++t) {
        int e = lane + t*64;
        yr[e] = (__bf16)((vals[t] - mean) * rstd * g[e] + b[e]);
    }
}

// ================= MFMA GEMM: C[M,N] = epi(A[M,K] @ B[K,N]) =================
// A: bf16 activations. B: f32 weights (cvt->bf16 at staging).
// 64x64 block tile, 4 waves of 32x32, mfma_f32_16x16x32_bf16.
// Output: bf16 for EPI_BIAS / EPI_BIAS_GELU (into H), f32 otherwise.
template<int EPI>
__global__ __launch_bounds__(256) void gemm_kernel(
    const __bf16* __restrict__ A, const float* __restrict__ Bw,
    const float* __restrict__ bias, const float* __restrict__ Rres,
    void* __restrict__ Cv, int M, int N, int K)
{
    __shared__ __bf16 As[64][40];         // [m][k]
    __shared__ unsigned int Bs[16][68];   // [k/2][n] packed {B[2k][n], B[2k+1][n]}
    const int tid  = threadIdx.x;
    const int lane = tid & 63, wave = tid >> 6;
    const int m0 = blockIdx.y << 6, n0 = blockIdx.x << 6;
    const int wm = (wave >> 1) << 5, wn = (wave & 1) << 5;
    const int q  = lane >> 4, mr = lane & 15;
    f32x4 acc[2][2];
    #pragma unroll
    for (int i = 0; i < 2; ++i)
        #pragma unroll
        for (int j = 0; j < 2; ++j)
            acc[i][j] = (f32x4){0.f, 0.f, 0.f, 0.f};

    const int arow = tid >> 2, acol = (tid & 3) << 3;      // A: 64 rows x 32 k
    const int bkp  = tid >> 4, bnc  = (tid & 15) << 2;     // B: 16 kpairs x 64 n
    const bool arow_ok = (m0 + arow) < M;
    const __bf16* Ap = A + (size_t)(m0 + arow) * K + acol;
    const float*  Bp = Bw + (size_t)(2*bkp) * N + n0 + bnc;

    for (int k0 = 0; k0 < K; k0 += 32) {
        // ---- global loads ----
        bf16x8 apack;
        if (arow_ok) {
            apack = *(const bf16x8*)(Ap + k0);
        } else {
            #pragma unroll
            for (int j = 0; j < 8; ++j) apack[j] = (__bf16)0.f;
        }
        const float* r0 = Bp + (size_t)k0 * N;
        float4 ra = *(const float4*)r0;
        float4 rb = *(const float4*)(r0 + N);
        unsigned int p0 = pack_bf2(ra.x, rb.x);
        unsigned int p1 = pack_bf2(ra.y, rb.y);
        unsigned int p2 = pack_bf2(ra.z, rb.z);
        unsigned int p3 = pack_bf2(ra.w, rb.w);
        // ---- LDS stage ----
        *(bf16x8*)&As[arow][acol] = apack;
        *(uint4*)&Bs[bkp][bnc] = make_uint4(p0, p1, p2, p3);
        __syncthreads();
        // ---- fragments ----
        bf16x8 af0 = *(const bf16x8*)&As[wm + mr][q*8];
        bf16x8 af1 = *(const bf16x8*)&As[wm + 16 + mr][q*8];
        bf16x8 bf0, bf1;
        #pragma unroll
        for (int jj = 0; jj < 4; ++jj) {
            unsigned int u0 = Bs[q*4 + jj][wn + mr];
            unsigned int u1 = Bs[q*4 + jj][wn + 16 + mr];
            bf0[2*jj]   = bf_from_bits(u0 & 0xffffu);
            bf0[2*jj+1] = bf_from_bits(u0 >> 16);
            bf1[2*jj]   = bf_from_bits(u1 & 0xffffu);
            bf1[2*jj+1] = bf_from_bits(u1 >> 16);
        }
        acc[0][0] = __builtin_amdgcn_mfma_f32_16x16x32_bf16(af0, bf0, acc[0][0], 0, 0, 0);
        acc[0][1] = __builtin_amdgcn_mfma_f32_16x16x32_bf16(af0, bf1, acc[0][1], 0, 0, 0);
        acc[1][0] = __builtin_amdgcn_mfma_f32_16x16x32_bf16(af1, bf0, acc[1][0], 0, 0, 0);
        acc[1][1] = __builtin_amdgcn_mfma_f32_16x16x32_bf16(af1, bf1, acc[1][1], 0, 0, 0);
        __syncthreads();
    }
    // ---- epilogue ----
    #pragma unroll
    for (int si = 0; si < 2; ++si) {
        #pragma unroll
        for (int sj = 0; sj < 2; ++sj) {
            int n = n0 + wn + sj*16 + mr;
            float bv = 0.f;
            if constexpr (EPI != EPI_NONE) bv = bias[n];
            #pragma unroll
            for (int r = 0; r < 4; ++r) {
                int m = m0 + wm + si*16 + q*4 + r;
                if (m < M) {
                    float v = acc[si][sj][r] + bv;
                    if constexpr (EPI == EPI_BIAS_GELU)
                        v = 0.5f * v * (1.f + erff(v * 0.70710678118654752f));
                    if constexpr (EPI == EPI_BIAS_RES)
                        v += Rres[(size_t)m * N + n];
                    if constexpr (EPI == EPI_BIAS || EPI == EPI_BIAS_GELU)
                        ((__bf16*)Cv)[(size_t)m * N + n] = (__bf16)v;
                    else
                        ((float*)Cv)[(size_t)m * N + n] = v;
                }
            }
        }
    }
}

// ================= fused attention (per (b,h,quarter-of-queries)) =================
// qkv: [1568, 1536] bf16 (q|k|v each 512 = 8 heads x 64). y2: [1568, 512] bf16.
__global__ __launch_bounds__(256) void attn_kernel(
    const __bf16* __restrict__ qkv, const float* __restrict__ tab,
    const int* __restrict__ rpe, __bf16* __restrict__ y2)
{
    __shared__ __bf16 Ks[196][70];   // stride 70 -> conflict-free reads
    __shared__ __bf16 Vs[196][70];
    __shared__ float  ps[4][200];
    __shared__ float  qs[4][64];
    int blk = blockIdx.x;                 // b*32 + h*4 + qg
    int qg = blk & 3, h = (blk >> 2) & 7, b = blk >> 5;
    int tid = threadIdx.x;
    // stage K,V: u32 granules (2 bf16) to keep LDS stores aligned at stride 70
    for (int i = tid; i < 196*32; i += 256) {
        int n = i >> 5, j = i & 31;
        const __bf16* base = qkv + ((size_t)(b*Np + n))*1536 + h*64 + 2*j;
        ((unsigned int*)&Ks[n][0])[j] = *(const unsigned int*)(base + 512);
        ((unsigned int*)&Vs[n][0])[j] = *(const unsigned int*)(base + 1024);
    }
    __syncthreads();
    int lane = tid & 63, wave = tid >> 6;
    for (int qq = wave; qq < 49; qq += 4) {
        int qi = qg*49 + qq;
        size_t qbase = ((size_t)(b*Np + qi))*1536 + h*64;
        qs[wave][lane] = (float)qkv[qbase + lane] * 0.125f;   // wave-local LDS RAW (in-order DS)
        int key_r[4]; float accr[4] = {0.f, 0.f, 0.f, 0.f};
        #pragma unroll
        for (int r = 0; r < 4; ++r) key_r[r] = min(lane + r*64, 195);
        for (int d = 0; d < 64; ++d) {
            float qv = qs[wave][d];
            #pragma unroll
            for (int r = 0; r < 4; ++r)
                accr[r] += qv * (float)Ks[key_r[r]][d];
        }
        const int* rrow = rpe + qi * Np;
        float vals[4];
        #pragma unroll
        for (int r = 0; r < 4; ++r) {
            int key = lane + r*64;
            if (key < 196) vals[r] = accr[r] + tab[rrow[key]*8 + h];
            else           vals[r] = -1e30f;
        }
        float m = fmaxf(fmaxf(vals[0], vals[1]), fmaxf(vals[2], vals[3]));
        #pragma unroll
        for (int o = 32; o > 0; o >>= 1) m = fmaxf(m, __shfl_xor(m, o, 64));
        float p[4]; float sum = 0.f;
        #pragma unroll
        for (int r = 0; r < 4; ++r) { p[r] = expf(vals[r] - m); sum += p[r]; }
        #pragma unroll
        for (int o = 32; o > 0; o >>= 1) sum += __shfl_xor(sum, o, 64);
        float inv = 1.f / sum;
        #pragma unroll
        for (int r = 0; r < 4; ++r) {
            int key = lane + r*64;
            if (key < 196) ps[wave][key] = p[r] * inv;
        }
        float acc = 0.f;
        for (int j = 0; j < 196; ++j)
            acc += ps[wave][j] * (float)Vs[j][lane];
        y2[((size_t)(b*Np + qi))*512 + h*64 + lane] = (__bf16)acc;
    }
}

// ================= ape add =================
__global__ __launch_bounds__(256) void add_ape_kernel(float* __restrict__ x,
                                                      const float* __restrict__ ape)
{
    int i = blockIdx.x * 256 + threadIdx.x;
    if (i < 1568*512) x[i] += ape[i % (Np*512)];
}

// ================= launcher =================
extern "C" void kernel_launch(void* const* d_in, const int* in_sizes, int n_in,
                              void* d_out, int out_size, void* d_ws, size_t ws_size,
                              hipStream_t stream)
{
    typedef const float* fp;
    fp image  = (fp)d_in[0];
    fp conv_w = (fp)d_in[1];  fp conv_b = (fp)d_in[2];
    fp pn_g   = (fp)d_in[3];  fp pn_b   = (fp)d_in[4];
    fp s1_ng  = (fp)d_in[5];  fp s1_nb  = (fp)d_in[6];
    fp s1_w1  = (fp)d_in[7];  fp s1_b1  = (fp)d_in[8];
    fp s1_w2  = (fp)d_in[9];  fp s1_b2  = (fp)d_in[10];
    fp s2_ng  = (fp)d_in[11]; fp s2_nb  = (fp)d_in[12];
    fp s2_w1  = (fp)d_in[13]; fp s2_b1  = (fp)d_in[14];
    fp s2_w2  = (fp)d_in[15]; fp s2_b2  = (fp)d_in[16];
    fp pm1_ng = (fp)d_in[17]; fp pm1_nb = (fp)d_in[18]; fp pm1_rw = (fp)d_in[19];
    fp pm2_ng = (fp)d_in[20]; fp pm2_nb = (fp)d_in[21]; fp pm2_rw = (fp)d_in[22];
    fp ape    = (fp)d_in[23];
    fp n1g    = (fp)d_in[24]; fp n1b    = (fp)d_in[25];
    fp qkvw   = (fp)d_in[26]; fp qkvb   = (fp)d_in[27];
    fp tab    = (fp)d_in[28];
    fp projw  = (fp)d_in[29]; fp projb  = (fp)d_in[30];
    fp n2g    = (fp)d_in[31]; fp n2b    = (fp)d_in[32];
    fp w1     = (fp)d_in[33]; fp b1     = (fp)d_in[34];
    fp w2     = (fp)d_in[35]; fp b2     = (fp)d_in[36];
    const int* rpe = (const int*)d_in[37];

    float*  X = (float*)d_ws;                 // 3,211,264 f32  (12.8 MB) residual, fp32
    __bf16* H = (__bf16*)(X + 3211264);       // 9,633,792 bf16 (19.3 MB) hidden/qkv
    __bf16* Y = H + 9633792;                  // 3,211,264 bf16 ( 6.4 MB) LN out / attn out

    // patch embed + pixel LN
    conv_ln_kernel<<<Bb*56*56, 128, 0, stream>>>(image, conv_w, conv_b, pn_g, pn_b, X);

    // stage 1: 3 MLP blocks on 25088 tokens, dim 128
    for (int t = 0; t < 3; ++t) {
        ln_kernel<<<25088/4, 256, 0, stream>>>(X, s1_ng + t*128, s1_nb + t*128, Y, 25088, 128);
        gemm_kernel<EPI_BIAS_GELU><<<dim3(384/64, 25088/64), 256, 0, stream>>>(
            Y, s1_w1 + (size_t)t*128*384, s1_b1 + t*384, nullptr, H, 25088, 384, 128);
        gemm_kernel<EPI_BIAS_RES><<<dim3(128/64, 25088/64), 256, 0, stream>>>(
            H, s1_w2 + (size_t)t*384*128, s1_b2 + t*128, X, X, 25088, 128, 384);
    }
    // merge 1: -> 6272 rows, dim 512 -> proj 256
    merge1_ln_kernel<<<6272/4, 256, 0, stream>>>(X, pm1_ng, pm1_nb, Y);
    gemm_kernel<EPI_NONE><<<dim3(256/64, 6272/64), 256, 0, stream>>>(
        Y, pm1_rw, nullptr, nullptr, X, 6272, 256, 512);
    // stage 2: 3 MLP blocks on 6272 rows, dim 256
    for (int t = 0; t < 3; ++t) {
        ln_kernel<<<6272/4, 256, 0, stream>>>(X, s2_ng + t*256, s2_nb + t*256, Y, 6272, 256);
        gemm_kernel<EPI_BIAS_GELU><<<dim3(768/64, 6272/64), 256, 0, stream>>>(
            Y, s2_w1 + (size_t)t*256*768, s2_b1 + t*768, nullptr, H, 6272, 768, 256);
        gemm_kernel<EPI_BIAS_RES><<<dim3(256/64, 6272/64), 256, 0, stream>>>(
            H, s2_w2 + (size_t)t*768*256, s2_b2 + t*256, X, X, 6272, 256, 768);
    }
    // merge 2: -> 1568 tokens, dim 1024 -> proj 512; + ape
    merge2_ln_kernel<<<1568/4, 256, 0, stream>>>(X, pm2_ng, pm2_nb, Y);
    gemm_kernel<EPI_NONE><<<dim3(512/64, (1568+63)/64), 256, 0, stream>>>(
        Y, pm2_rw, nullptr, nullptr, X, 1568, 512, 1024);
    add_ape_kernel<<<(1568*512+255)/256, 256, 0, stream>>>(X, ape);

    // 24 transformer blocks
    const int MT = (1568 + 63) / 64;   // 25
    for (int l = 0; l < DEPTH; ++l) {
        ln_kernel<<<392, 256, 0, stream>>>(X, n1g + l*EMB, n1b + l*EMB, Y, 1568, EMB);
        gemm_kernel<EPI_BIAS><<<dim3(1536/64, MT), 256, 0, stream>>>(
            Y, qkvw + (size_t)l*EMB*1536, qkvb + (size_t)l*1536, nullptr, H, 1568, 1536, EMB);
        attn_kernel<<<256, 256, 0, stream>>>(H, tab + (size_t)l*RPEL*HEADS, rpe, Y);
        gemm_kernel<EPI_BIAS_RES><<<dim3(512/64, MT), 256, 0, stream>>>(
            Y, projw + (size_t)l*EMB*EMB, projb + (size_t)l*EMB, X, X, 1568, EMB, EMB);
        ln_kernel<<<392, 256, 0, stream>>>(X, n2g + l*EMB, n2b + l*EMB, Y, 1568, EMB);
        gemm_kernel<EPI_BIAS_GELU><<<dim3(2048/64, MT), 256, 0, stream>>>(
            Y, w1 + (size_t)l*EMB*2048, b1 + (size_t)l*2048, nullptr, H, 1568, 2048, EMB);
        float* Cout = (l == DEPTH-1) ? (float*)d_out : X;
        gemm_kernel<EPI_BIAS_RES><<<dim3(512/64, MT), 256, 0, stream>>>(
            H, w2 + (size_t)l*2048*EMB, b2 + (size_t)l*EMB, X, Cout, 1568, EMB, 2048);
    }
}

// Round 3
// 3916.478 us; speedup vs baseline: 1.3325x; 1.3325x over previous
//
#include <hip/hip_runtime.h>
#include <hip/hip_bf16.h>

// ---------------- constants ----------------
#define Bb    8
#define IMG   224
#define Hp    14
#define Np    196      // tokens per image
#define D4    128
#define D8    256
#define EMB   512
#define HEADS 8
#define HD    64
#define RPEL  729
#define DEPTH 24
#define EPS   1e-5f

constexpr int EPI_NONE = 0, EPI_BIAS = 1, EPI_BIAS_GELU = 2, EPI_BIAS_RES = 3;

typedef __bf16 bf16x8 __attribute__((ext_vector_type(8)));
typedef float  f32x4  __attribute__((ext_vector_type(4)));

static __device__ __forceinline__ unsigned int pack_bf2(float lo, float hi) {
    union { __bf16 b; unsigned short u; } a, c;
    a.b = (__bf16)lo; c.b = (__bf16)hi;
    return (unsigned int)a.u | ((unsigned int)c.u << 16);
}

// ================= conv 4x4/4 + patchify + per-pixel LN =================
__global__ __launch_bounds__(128) void conv_ln_kernel(
    const float* __restrict__ img, const float* __restrict__ cw,
    const float* __restrict__ cb,  const float* __restrict__ png,
    const float* __restrict__ pnb, float* __restrict__ xout)
{
    int p = blockIdx.x;                 // b*3136 + h'*56 + w'
    int b = p / 3136, rem = p % 3136;
    int hh = rem / 56, ww = rem % 56;
    __shared__ float win[48];
    __shared__ float red[4];
    int t = threadIdx.x;
    if (t < 48) {
        int ic = t >> 4, kh = (t >> 2) & 3, kw = t & 3;
        win[t] = img[(((size_t)b*3 + ic)*224 + hh*4 + kh)*224 + ww*4 + kw];
    }
    __syncthreads();
    float acc = cb[t];
    const float* wrow = cw + (size_t)t * 48;
    #pragma unroll
    for (int r = 0; r < 48; ++r) acc += win[r] * wrow[r];
    float s = acc, ss = acc * acc;
    #pragma unroll
    for (int o = 32; o > 0; o >>= 1) { s += __shfl_xor(s, o, 64); ss += __shfl_xor(ss, o, 64); }
    int wv = t >> 6;
    if ((t & 63) == 0) { red[wv*2] = s; red[wv*2+1] = ss; }
    __syncthreads();
    s = red[0] + red[2]; ss = red[1] + red[3];
    float mean = s * (1.f/128.f);
    float rstd = rsqrtf(ss * (1.f/128.f) - mean*mean + EPS);
    float v = (acc - mean) * rstd * png[t] + pnb[t];
    int hp = hh >> 2, ih = hh & 3, wp = ww >> 2, iw = ww & 3;
    int bn = b * Np + hp * Hp + wp;
    xout[((size_t)bn*16 + ih*4 + iw)*128 + t] = v;
}

// ================= generic LayerNorm: one wave per row, f32 in -> bf16 out =================
__global__ __launch_bounds__(256) void ln_kernel(
    const float* __restrict__ x, const float* __restrict__ g,
    const float* __restrict__ b, __bf16* __restrict__ y, int M, int D)
{
    int wave = threadIdx.x >> 6, lane = threadIdx.x & 63;
    int row = blockIdx.x * 4 + wave;
    if (row >= M) return;
    const float* xr = x + (size_t)row * D;
    float s = 0.f, ss = 0.f;
    for (int i = lane; i < D; i += 64) { float v = xr[i]; s += v; ss += v*v; }
    #pragma unroll
    for (int o = 32; o > 0; o >>= 1) { s += __shfl_xor(s, o, 64); ss += __shfl_xor(ss, o, 64); }
    float inv = 1.f / (float)D;
    float mean = s * inv;
    float rstd = rsqrtf(ss * inv - mean*mean + EPS);
    __bf16* yr = y + (size_t)row * D;
    for (int i = lane; i < D; i += 64)
        yr[i] = (__bf16)((xr[i] - mean) * rstd * g[i] + b[i]);
}

// ================= merge1: gather 2x2 inner (dim128->512) + LN =================
__global__ __launch_bounds__(256) void merge1_ln_kernel(
    const float* __restrict__ x, const float* __restrict__ g,
    const float* __restrict__ b, __bf16* __restrict__ y)
{
    int wave = threadIdx.x >> 6, lane = threadIdx.x & 63;
    int row = blockIdx.x * 4 + wave;
    if (row >= 6272) return;
    int j2 = row & 1, i2 = (row >> 1) & 1, bn = row >> 2;
    float vals[8]; float s = 0.f, ss = 0.f;
    #pragma unroll
    for (int t = 0; t < 8; ++t) {
        int e = lane + t*64;
        int k = e >> 7, c = e & 127;
        int ih = 2*i2 + (k & 1), iw = 2*j2 + (k >> 1);
        float v = x[((size_t)bn*16 + ih*4 + iw)*128 + c];
        vals[t] = v; s += v; ss += v*v;
    }
    #pragma unroll
    for (int o = 32; o > 0; o >>= 1) { s += __shfl_xor(s, o, 64); ss += __shfl_xor(ss, o, 64); }
    float mean = s * (1.f/512.f);
    float rstd = rsqrtf(ss * (1.f/512.f) - mean*mean + EPS);
    __bf16* yr = y + (size_t)row * 512;
    #pragma unroll
    for (int t = 0; t < 8; ++t) {
        int e = lane + t*64;
        yr[e] = (__bf16)((vals[t] - mean) * rstd * g[e] + b[e]);
    }
}

// ================= merge2: gather 2x2 tokens (dim256->1024) + LN =================
__global__ __launch_bounds__(256) void merge2_ln_kernel(
    const float* __restrict__ x, const float* __restrict__ g,
    const float* __restrict__ b, __bf16* __restrict__ y)
{
    int wave = threadIdx.x >> 6, lane = threadIdx.x & 63;
    int row = blockIdx.x * 4 + wave;
    if (row >= 1568) return;
    float vals[16]; float s = 0.f, ss = 0.f;
    #pragma unroll
    for (int t = 0; t < 16; ++t) {
        int e = lane + t*64;
        int k = e >> 8, c = e & 255;
        float v = x[((size_t)row*4 + (k & 1)*2 + (k >> 1))*256 + c];
        vals[t] = v; s += v; ss += v*v;
    }
    #pragma unroll
    for (int o = 32; o > 0; o >>= 1) { s += __shfl_xor(s, o, 64); ss += __shfl_xor(ss, o, 64); }
    float mean = s * (1.f/1024.f);
    float rstd = rsqrtf(ss * (1.f/1024.f) - mean*mean + EPS);
    __bf16* yr = y + (size_t)row * 1024;
    #pragma unroll
    for (int t = 0; t < 16; ++t) {
        int e = lane + t*64;
        yr[e] = (__bf16)((vals[t] - mean) * rstd * g[e] + b[e]);
    }
}

// ================= MFMA GEMM: C[M,N] = epi(A[M,K] @ B[K,N]) =================
template<int EPI>
__global__ __launch_bounds__(256) void gemm_kernel(
    const __bf16* __restrict__ A, const float* __restrict__ Bw,
    const float* __restrict__ bias, const float* __restrict__ Rres,
    void* __restrict__ Cv, int M, int N, int K)
{
    __shared__ __bf16 As[64][40];         // [m][k]
    __shared__ unsigned int Bs[16][68];   // [k/2][n] packed {B[2k][n], B[2k+1][n]}
    const int tid  = threadIdx.x;
    const int lane = tid & 63, wave = tid >> 6;
    const int m0 = blockIdx.y << 6, n0 = blockIdx.x << 6;
    const int wm = (wave >> 1) << 5, wn = (wave & 1) << 5;
    const int q  = lane >> 4, mr = lane & 15;
    f32x4 acc[2][2];
    #pragma unroll
    for (int i = 0; i < 2; ++i)
        #pragma unroll
        for (int j = 0; j < 2; ++j)
            acc[i][j] = (f32x4){0.f, 0.f, 0.f, 0.f};

    const int arow = tid >> 2, acol = (tid & 3) << 3;      // A: 64 rows x 32 k
    const int bkp  = tid >> 4, bnc  = (tid & 15) << 2;     // B: 16 kpairs x 64 n
    const bool arow_ok = (m0 + arow) < M;
    const __bf16* Ap = A + (size_t)(m0 + arow) * K + acol;
    const float*  Bp = Bw + (size_t)(2*bkp) * N + n0 + bnc;

    for (int k0 = 0; k0 < K; k0 += 32) {
        bf16x8 apack;
        if (arow_ok) {
            apack = *(const bf16x8*)(Ap + k0);
        } else {
            #pragma unroll
            for (int j = 0; j < 8; ++j) apack[j] = (__bf16)0.f;
        }
        const float* r0 = Bp + (size_t)k0 * N;
        float4 ra = *(const float4*)r0;
        float4 rb = *(const float4*)(r0 + N);
        unsigned int p0 = pack_bf2(ra.x, rb.x);
        unsigned int p1 = pack_bf2(ra.y, rb.y);
        unsigned int p2 = pack_bf2(ra.z, rb.z);
        unsigned int p3 = pack_bf2(ra.w, rb.w);
        *(bf16x8*)&As[arow][acol] = apack;
        *(uint4*)&Bs[bkp][bnc] = make_uint4(p0, p1, p2, p3);
        __syncthreads();
        bf16x8 af0 = *(const bf16x8*)&As[wm + mr][q*8];
        bf16x8 af1 = *(const bf16x8*)&As[wm + 16 + mr][q*8];
        union BU { unsigned int u[4]; bf16x8 v; } b0, b1;
        #pragma unroll
        for (int jj = 0; jj < 4; ++jj) {
            b0.u[jj] = Bs[q*4 + jj][wn + mr];
            b1.u[jj] = Bs[q*4 + jj][wn + 16 + mr];
        }
        acc[0][0] = __builtin_amdgcn_mfma_f32_16x16x32_bf16(af0, b0.v, acc[0][0], 0, 0, 0);
        acc[0][1] = __builtin_amdgcn_mfma_f32_16x16x32_bf16(af0, b1.v, acc[0][1], 0, 0, 0);
        acc[1][0] = __builtin_amdgcn_mfma_f32_16x16x32_bf16(af1, b0.v, acc[1][0], 0, 0, 0);
        acc[1][1] = __builtin_amdgcn_mfma_f32_16x16x32_bf16(af1, b1.v, acc[1][1], 0, 0, 0);
        __syncthreads();
    }
    #pragma unroll
    for (int si = 0; si < 2; ++si) {
        #pragma unroll
        for (int sj = 0; sj < 2; ++sj) {
            int n = n0 + wn + sj*16 + mr;
            float bv = 0.f;
            if constexpr (EPI != EPI_NONE) bv = bias[n];
            #pragma unroll
            for (int r = 0; r < 4; ++r) {
                int m = m0 + wm + si*16 + q*4 + r;
                if (m < M) {
                    float v = acc[si][sj][r] + bv;
                    if constexpr (EPI == EPI_BIAS_GELU)
                        v = 0.5f * v * (1.f + erff(v * 0.70710678118654752f));
                    if constexpr (EPI == EPI_BIAS_RES)
                        v += Rres[(size_t)m * N + n];
                    if constexpr (EPI == EPI_BIAS || EPI == EPI_BIAS_GELU)
                        ((__bf16*)Cv)[(size_t)m * N + n] = (__bf16)v;
                    else
                        ((float*)Cv)[(size_t)m * N + n] = v;
                }
            }
        }
    }
}

// ================= MFMA fused attention =================
// block = (b, h, qg); wave handles q-tile T = qg + 4*wave (16 queries), T<=12.
// S = Q@K^T via mfma (A,B frags straight from global qkv); softmax in-register
// (C-layout rows live in 16-lane groups); P -> per-wave LDS (A-layout);
// V staged transposed in LDS once per block; PV via mfma.
__global__ __launch_bounds__(256) void attn_kernel(
    const __bf16* __restrict__ qkv, const float* __restrict__ tab,
    const int* __restrict__ rpe, __bf16* __restrict__ y2)
{
    __shared__ __bf16 Vt[64][232];        // V^T: [d][key], 16B-aligned rows
    __shared__ __bf16 Pl[4][16][232];     // per-wave P tile [qrow][key]
    int blk = blockIdx.x;                 // b*32 + h*4 + qg
    int qg = blk & 3, h = (blk >> 2) & 7, b = blk >> 5;
    int tid = threadIdx.x;

    // ---- stage V transposed ----
    for (int i = tid; i < 196*8; i += 256) {
        int key = i >> 3, seg = i & 7;
        bf16x8 v = *(const bf16x8*)(qkv + ((size_t)(b*Np + key))*1536 + 1024 + h*64 + seg*8);
        #pragma unroll
        for (int j = 0; j < 8; ++j) Vt[seg*8 + j][key] = v[j];
    }
    // zero V pad keys 196..231
    {
        int d0 = tid >> 2, cs = tid & 3;
        #pragma unroll
        for (int j = 0; j < 9; ++j) Vt[d0][196 + cs*9 + j] = (__bf16)0.f;
    }
    __syncthreads();

    int lane = tid & 63, wave = tid >> 6;
    int T = qg + 4*wave;
    if (T > 12) return;
    int q = lane >> 4, mr = lane & 15;

    // zero P pad cols 196..231 (read region ends at 223)
    if (lane < 36) {
        #pragma unroll
        for (int r = 0; r < 16; ++r) Pl[wave][r][196 + lane] = (__bf16)0.f;
    }

    // ---- Q fragments (A-layout, direct from global) ----
    int qtok = b*Np + min(T*16 + mr, 195);
    const __bf16* qp = qkv + (size_t)qtok*1536 + h*64 + q*8;
    bf16x8 aq0 = *(const bf16x8*)qp;
    bf16x8 aq1 = *(const bf16x8*)(qp + 32);

    // ---- S = Q @ K^T : 13 key-tiles x 2 k-steps ----
    f32x4 sacc[13];
    #pragma unroll
    for (int nt = 0; nt < 13; ++nt) {
        int ktok = b*Np + min(nt*16 + mr, 195);
        const __bf16* kp = qkv + (size_t)ktok*1536 + 512 + h*64 + q*8;
        bf16x8 bk0 = *(const bf16x8*)kp;
        bf16x8 bk1 = *(const bf16x8*)(kp + 32);
        f32x4 z = (f32x4){0.f, 0.f, 0.f, 0.f};
        z = __builtin_amdgcn_mfma_f32_16x16x32_bf16(aq0, bk0, z, 0, 0, 0);
        sacc[nt] = __builtin_amdgcn_mfma_f32_16x16x32_bf16(aq1, bk1, z, 0, 0, 0);
    }

    // ---- bias + softmax per row (rows = q*4 + r, within 16-lane group) ----
    #pragma unroll
    for (int r = 0; r < 4; ++r) {
        int qi = T*16 + q*4 + r;
        const int* rrow = rpe + (size_t)min(qi, 195) * 196;
        float vals[13];
        #pragma unroll
        for (int nt = 0; nt < 13; ++nt) {
            int col = nt*16 + mr;
            float bv = tab[rrow[min(col, 195)]*8 + h];
            float v = sacc[nt][r] * 0.125f + bv;
            vals[nt] = (col < 196) ? v : -3.0e38f;
        }
        float m = vals[0];
        #pragma unroll
        for (int nt = 1; nt < 13; ++nt) m = fmaxf(m, vals[nt]);
        #pragma unroll
        for (int o = 8; o > 0; o >>= 1) m = fmaxf(m, __shfl_xor(m, o, 64));
        float s = 0.f, p[13];
        #pragma unroll
        for (int nt = 0; nt < 13; ++nt) { p[nt] = __expf(vals[nt] - m); s += p[nt]; }
        #pragma unroll
        for (int o = 8; o > 0; o >>= 1) s += __shfl_xor(s, o, 64);
        float inv = 1.f / s;
        #pragma unroll
        for (int nt = 0; nt < 13; ++nt)
            Pl[wave][q*4 + r][nt*16 + mr] = (__bf16)(p[nt] * inv);
    }

    // ---- O = P @ V : 7 k-steps (keys) x 4 d-tiles ----
    f32x4 oacc[4];
    #pragma unroll
    for (int nt = 0; nt < 4; ++nt) oacc[nt] = (f32x4){0.f, 0.f, 0.f, 0.f};
    #pragma unroll
    for (int ks = 0; ks < 7; ++ks) {
        bf16x8 ap = *(const bf16x8*)&Pl[wave][mr][ks*32 + q*8];
        #pragma unroll
        for (int nt = 0; nt < 4; ++nt) {
            bf16x8 bv = *(const bf16x8*)&Vt[nt*16 + mr][ks*32 + q*8];
            oacc[nt] = __builtin_amdgcn_mfma_f32_16x16x32_bf16(ap, bv, oacc[nt], 0, 0, 0);
        }
    }

    // ---- store O ----
    #pragma unroll
    for (int nt = 0; nt < 4; ++nt) {
        #pragma unroll
        for (int r = 0; r < 4; ++r) {
            int qi = T*16 + q*4 + r;
            if (qi < 196)
                y2[((size_t)(b*Np + qi))*512 + h*64 + nt*16 + mr] = (__bf16)oacc[nt][r];
        }
    }
}

// ================= ape add =================
__global__ __launch_bounds__(256) void add_ape_kernel(float* __restrict__ x,
                                                      const float* __restrict__ ape)
{
    int i = blockIdx.x * 256 + threadIdx.x;
    if (i < 1568*512) x[i] += ape[i % (Np*512)];
}

// ================= launcher =================
extern "C" void kernel_launch(void* const* d_in, const int* in_sizes, int n_in,
                              void* d_out, int out_size, void* d_ws, size_t ws_size,
                              hipStream_t stream)
{
    typedef const float* fp;
    fp image  = (fp)d_in[0];
    fp conv_w = (fp)d_in[1];  fp conv_b = (fp)d_in[2];
    fp pn_g   = (fp)d_in[3];  fp pn_b   = (fp)d_in[4];
    fp s1_ng  = (fp)d_in[5];  fp s1_nb  = (fp)d_in[6];
    fp s1_w1  = (fp)d_in[7];  fp s1_b1  = (fp)d_in[8];
    fp s1_w2  = (fp)d_in[9];  fp s1_b2  = (fp)d_in[10];
    fp s2_ng  = (fp)d_in[11]; fp s2_nb  = (fp)d_in[12];
    fp s2_w1  = (fp)d_in[13]; fp s2_b1  = (fp)d_in[14];
    fp s2_w2  = (fp)d_in[15]; fp s2_b2  = (fp)d_in[16];
    fp pm1_ng = (fp)d_in[17]; fp pm1_nb = (fp)d_in[18]; fp pm1_rw = (fp)d_in[19];
    fp pm2_ng = (fp)d_in[20]; fp pm2_nb = (fp)d_in[21]; fp pm2_rw = (fp)d_in[22];
    fp ape    = (fp)d_in[23];
    fp n1g    = (fp)d_in[24]; fp n1b    = (fp)d_in[25];
    fp qkvw   = (fp)d_in[26]; fp qkvb   = (fp)d_in[27];
    fp tab    = (fp)d_in[28];
    fp projw  = (fp)d_in[29]; fp projb  = (fp)d_in[30];
    fp n2g    = (fp)d_in[31]; fp n2b    = (fp)d_in[32];
    fp w1     = (fp)d_in[33]; fp b1     = (fp)d_in[34];
    fp w2     = (fp)d_in[35]; fp b2     = (fp)d_in[36];
    const int* rpe = (const int*)d_in[37];

    float*  X = (float*)d_ws;                 // 3,211,264 f32  residual
    __bf16* H = (__bf16*)(X + 3211264);       // 9,633,792 bf16 hidden/qkv
    __bf16* Y = H + 9633792;                  // 3,211,264 bf16 LN out / attn out

    conv_ln_kernel<<<Bb*56*56, 128, 0, stream>>>(image, conv_w, conv_b, pn_g, pn_b, X);

    for (int t = 0; t < 3; ++t) {
        ln_kernel<<<25088/4, 256, 0, stream>>>(X, s1_ng + t*128, s1_nb + t*128, Y, 25088, 128);
        gemm_kernel<EPI_BIAS_GELU><<<dim3(384/64, 25088/64), 256, 0, stream>>>(
            Y, s1_w1 + (size_t)t*128*384, s1_b1 + t*384, nullptr, H, 25088, 384, 128);
        gemm_kernel<EPI_BIAS_RES><<<dim3(128/64, 25088/64), 256, 0, stream>>>(
            H, s1_w2 + (size_t)t*384*128, s1_b2 + t*128, X, X, 25088, 128, 384);
    }
    merge1_ln_kernel<<<6272/4, 256, 0, stream>>>(X, pm1_ng, pm1_nb, Y);
    gemm_kernel<EPI_NONE><<<dim3(256/64, 6272/64), 256, 0, stream>>>(
        Y, pm1_rw, nullptr, nullptr, X, 6272, 256, 512);
    for (int t = 0; t < 3; ++t) {
        ln_kernel<<<6272/4, 256, 0, stream>>>(X, s2_ng + t*256, s2_nb + t*256, Y, 6272, 256);
        gemm_kernel<EPI_BIAS_GELU><<<dim3(768/64, 6272/64), 256, 0, stream>>>(
            Y, s2_w1 + (size_t)t*256*768, s2_b1 + t*768, nullptr, H, 6272, 768, 256);
        gemm_kernel<EPI_BIAS_RES><<<dim3(256/64, 6272/64), 256, 0, stream>>>(
            H, s2_w2 + (size_t)t*768*256, s2_b2 + t*256, X, X, 6272, 256, 768);
    }
    merge2_ln_kernel<<<1568/4, 256, 0, stream>>>(X, pm2_ng, pm2_nb, Y);
    gemm_kernel<EPI_NONE><<<dim3(512/64, (1568+63)/64), 256, 0, stream>>>(
        Y, pm2_rw, nullptr, nullptr, X, 1568, 512, 1024);
    add_ape_kernel<<<(1568*512+255)/256, 256, 0, stream>>>(X, ape);

    const int MT = (1568 + 63) / 64;   // 25
    for (int l = 0; l < DEPTH; ++l) {
        ln_kernel<<<392, 256, 0, stream>>>(X, n1g + l*EMB, n1b + l*EMB, Y, 1568, EMB);
        gemm_kernel<EPI_BIAS><<<dim3(1536/64, MT), 256, 0, stream>>>(
            Y, qkvw + (size_t)l*EMB*1536, qkvb + (size_t)l*1536, nullptr, H, 1568, 1536, EMB);
        attn_kernel<<<256, 256, 0, stream>>>(H, tab + (size_t)l*RPEL*HEADS, rpe, Y);
        gemm_kernel<EPI_BIAS_RES><<<dim3(512/64, MT), 256, 0, stream>>>(
            Y, projw + (size_t)l*EMB*EMB, projb + (size_t)l*EMB, X, X, 1568, EMB, EMB);
        ln_kernel<<<392, 256, 0, stream>>>(X, n2g + l*EMB, n2b + l*EMB, Y, 1568, EMB);
        gemm_kernel<EPI_BIAS_GELU><<<dim3(2048/64, MT), 256, 0, stream>>>(
            Y, w1 + (size_t)l*EMB*2048, b1 + (size_t)l*2048, nullptr, H, 1568, 2048, EMB);
        float* Cout = (l == DEPTH-1) ? (float*)d_out : X;
        gemm_kernel<EPI_BIAS_RES><<<dim3(512/64, MT), 256, 0, stream>>>(
            H, w2 + (size_t)l*2048*EMB, b2 + (size_t)l*EMB, X, Cout, 1568, EMB, 2048);
    }
}

// Round 4
// 3644.323 us; speedup vs baseline: 1.4320x; 1.0747x over previous
//
#include <hip/hip_runtime.h>
#include <hip/hip_bf16.h>

// ---------------- constants ----------------
#define Bb    8
#define IMG   224
#define Hp    14
#define Np    196      // tokens per image
#define D4    128
#define D8    256
#define EMB   512
#define HEADS 8
#define HD    64
#define RPEL  729
#define DEPTH 24
#define EPS   1e-5f

constexpr int EPI_NONE = 0, EPI_BIAS = 1, EPI_BIAS_GELU = 2, EPI_BIAS_RES = 3, EPI_ATOMIC = 4;

typedef __bf16 bf16x8 __attribute__((ext_vector_type(8)));
typedef float  f32x4  __attribute__((ext_vector_type(4)));

static __device__ __forceinline__ unsigned int pack_bf2(float lo, float hi) {
    union { __bf16 b; unsigned short u; } a, c;
    a.b = (__bf16)lo; c.b = (__bf16)hi;
    return (unsigned int)a.u | ((unsigned int)c.u << 16);
}
// load 8 contiguous f32, round to bf16x8
static __device__ __forceinline__ bf16x8 ld8f(const float* __restrict__ p) {
    float4 a = *(const float4*)p, b = *(const float4*)(p + 4);
    bf16x8 r;
    r[0] = (__bf16)a.x; r[1] = (__bf16)a.y; r[2] = (__bf16)a.z; r[3] = (__bf16)a.w;
    r[4] = (__bf16)b.x; r[5] = (__bf16)b.y; r[6] = (__bf16)b.z; r[7] = (__bf16)b.w;
    return r;
}

// ================= conv 4x4/4 + patchify + per-pixel LN =================
__global__ __launch_bounds__(128) void conv_ln_kernel(
    const float* __restrict__ img, const float* __restrict__ cw,
    const float* __restrict__ cb,  const float* __restrict__ png,
    const float* __restrict__ pnb, float* __restrict__ xout)
{
    int p = blockIdx.x;                 // b*3136 + h'*56 + w'
    int b = p / 3136, rem = p % 3136;
    int hh = rem / 56, ww = rem % 56;
    __shared__ float win[48];
    __shared__ float red[4];
    int t = threadIdx.x;
    if (t < 48) {
        int ic = t >> 4, kh = (t >> 2) & 3, kw = t & 3;
        win[t] = img[(((size_t)b*3 + ic)*224 + hh*4 + kh)*224 + ww*4 + kw];
    }
    __syncthreads();
    float acc = cb[t];
    const float* wrow = cw + (size_t)t * 48;
    #pragma unroll
    for (int r = 0; r < 48; ++r) acc += win[r] * wrow[r];
    float s = acc, ss = acc * acc;
    #pragma unroll
    for (int o = 32; o > 0; o >>= 1) { s += __shfl_xor(s, o, 64); ss += __shfl_xor(ss, o, 64); }
    int wv = t >> 6;
    if ((t & 63) == 0) { red[wv*2] = s; red[wv*2+1] = ss; }
    __syncthreads();
    s = red[0] + red[2]; ss = red[1] + red[3];
    float mean = s * (1.f/128.f);
    float rstd = rsqrtf(ss * (1.f/128.f) - mean*mean + EPS);
    float v = (acc - mean) * rstd * png[t] + pnb[t];
    int hp = hh >> 2, ih = hh & 3, wp = ww >> 2, iw = ww & 3;
    int bn = b * Np + hp * Hp + wp;
    xout[((size_t)bn*16 + ih*4 + iw)*128 + t] = v;
}

// ================= generic LayerNorm: one wave per row, f32 in -> bf16 out =================
__global__ __launch_bounds__(256) void ln_kernel(
    const float* __restrict__ x, const float* __restrict__ g,
    const float* __restrict__ b, __bf16* __restrict__ y, int M, int D)
{
    int wave = threadIdx.x >> 6, lane = threadIdx.x & 63;
    int row = blockIdx.x * 4 + wave;
    if (row >= M) return;
    const float* xr = x + (size_t)row * D;
    float s = 0.f, ss = 0.f;
    for (int i = lane; i < D; i += 64) { float v = xr[i]; s += v; ss += v*v; }
    #pragma unroll
    for (int o = 32; o > 0; o >>= 1) { s += __shfl_xor(s, o, 64); ss += __shfl_xor(ss, o, 64); }
    float inv = 1.f / (float)D;
    float mean = s * inv;
    float rstd = rsqrtf(ss * inv - mean*mean + EPS);
    __bf16* yr = y + (size_t)row * D;
    for (int i = lane; i < D; i += 64)
        yr[i] = (__bf16)((xr[i] - mean) * rstd * g[i] + b[i]);
}

// ================= merge1: gather 2x2 inner (dim128->512) + LN =================
__global__ __launch_bounds__(256) void merge1_ln_kernel(
    const float* __restrict__ x, const float* __restrict__ g,
    const float* __restrict__ b, __bf16* __restrict__ y)
{
    int wave = threadIdx.x >> 6, lane = threadIdx.x & 63;
    int row = blockIdx.x * 4 + wave;
    if (row >= 6272) return;
    int j2 = row & 1, i2 = (row >> 1) & 1, bn = row >> 2;
    float vals[8]; float s = 0.f, ss = 0.f;
    #pragma unroll
    for (int t = 0; t < 8; ++t) {
        int e = lane + t*64;
        int k = e >> 7, c = e & 127;
        int ih = 2*i2 + (k & 1), iw = 2*j2 + (k >> 1);
        float v = x[((size_t)bn*16 + ih*4 + iw)*128 + c];
        vals[t] = v; s += v; ss += v*v;
    }
    #pragma unroll
    for (int o = 32; o > 0; o >>= 1) { s += __shfl_xor(s, o, 64); ss += __shfl_xor(ss, o, 64); }
    float mean = s * (1.f/512.f);
    float rstd = rsqrtf(ss * (1.f/512.f) - mean*mean + EPS);
    __bf16* yr = y + (size_t)row * 512;
    #pragma unroll
    for (int t = 0; t < 8; ++t) {
        int e = lane + t*64;
        yr[e] = (__bf16)((vals[t] - mean) * rstd * g[e] + b[e]);
    }
}

// ================= merge2: gather 2x2 tokens (dim256->1024) + LN =================
__global__ __launch_bounds__(256) void merge2_ln_kernel(
    const float* __restrict__ x, const float* __restrict__ g,
    const float* __restrict__ b, __bf16* __restrict__ y)
{
    int wave = threadIdx.x >> 6, lane = threadIdx.x & 63;
    int row = blockIdx.x * 4 + wave;
    if (row >= 1568) return;
    float vals[16]; float s = 0.f, ss = 0.f;
    #pragma unroll
    for (int t = 0; t < 16; ++t) {
        int e = lane + t*64;
        int k = e >> 8, c = e & 255;
        float v = x[((size_t)row*4 + (k & 1)*2 + (k >> 1))*256 + c];
        vals[t] = v; s += v; ss += v*v;
    }
    #pragma unroll
    for (int o = 32; o > 0; o >>= 1) { s += __shfl_xor(s, o, 64); ss += __shfl_xor(ss, o, 64); }
    float mean = s * (1.f/1024.f);
    float rstd = rsqrtf(ss * (1.f/1024.f) - mean*mean + EPS);
    __bf16* yr = y + (size_t)row * 1024;
    #pragma unroll
    for (int t = 0; t < 16; ++t) {
        int e = lane + t*64;
        yr[e] = (__bf16)((vals[t] - mean) * rstd * g[e] + b[e]);
    }
}

// ================= MFMA GEMM: C[M,N] = epi(A[M,K] @ B[K,N]) =================
// EPI_ATOMIC: split-K over blockIdx.z (chunk kChunk); partial tile is
// atomicAdd-ed onto f32 Cv; bias added only by the z==0 block (Cv must be
// pre-initialized: zeros for fresh output, residual X for res-add fusion).
template<int EPI>
__global__ __launch_bounds__(256) void gemm_kernel(
    const __bf16* __restrict__ A, const float* __restrict__ Bw,
    const float* __restrict__ bias, const float* __restrict__ Rres,
    void* __restrict__ Cv, int M, int N, int K, int kChunk)
{
    __shared__ __bf16 As[64][40];         // [m][k]
    __shared__ unsigned int Bs[16][68];   // [k/2][n] packed {B[2k][n], B[2k+1][n]}
    const int tid  = threadIdx.x;
    const int lane = tid & 63, wave = tid >> 6;
    const int m0 = blockIdx.y << 6, n0 = blockIdx.x << 6;
    const int wm = (wave >> 1) << 5, wn = (wave & 1) << 5;
    const int q  = lane >> 4, mr = lane & 15;
    const int kstart = blockIdx.z * kChunk;
    const int kend   = min(kstart + kChunk, K);
    f32x4 acc[2][2];
    #pragma unroll
    for (int i = 0; i < 2; ++i)
        #pragma unroll
        for (int j = 0; j < 2; ++j)
            acc[i][j] = (f32x4){0.f, 0.f, 0.f, 0.f};

    const int arow = tid >> 2, acol = (tid & 3) << 3;      // A: 64 rows x 32 k
    const int bkp  = tid >> 4, bnc  = (tid & 15) << 2;     // B: 16 kpairs x 64 n
    const bool arow_ok = (m0 + arow) < M;
    const __bf16* Ap = A + (size_t)(m0 + arow) * K + acol;
    const float*  Bp = Bw + (size_t)(2*bkp) * N + n0 + bnc;

    for (int k0 = kstart; k0 < kend; k0 += 32) {
        bf16x8 apack;
        if (arow_ok) {
            apack = *(const bf16x8*)(Ap + k0);
        } else {
            #pragma unroll
            for (int j = 0; j < 8; ++j) apack[j] = (__bf16)0.f;
        }
        const float* r0 = Bp + (size_t)k0 * N;
        float4 ra = *(const float4*)r0;
        float4 rb = *(const float4*)(r0 + N);
        unsigned int p0 = pack_bf2(ra.x, rb.x);
        unsigned int p1 = pack_bf2(ra.y, rb.y);
        unsigned int p2 = pack_bf2(ra.z, rb.z);
        unsigned int p3 = pack_bf2(ra.w, rb.w);
        *(bf16x8*)&As[arow][acol] = apack;
        *(uint4*)&Bs[bkp][bnc] = make_uint4(p0, p1, p2, p3);
        __syncthreads();
        bf16x8 af0 = *(const bf16x8*)&As[wm + mr][q*8];
        bf16x8 af1 = *(const bf16x8*)&As[wm + 16 + mr][q*8];
        union BU { unsigned int u[4]; bf16x8 v; } b0, b1;
        #pragma unroll
        for (int jj = 0; jj < 4; ++jj) {
            b0.u[jj] = Bs[q*4 + jj][wn + mr];
            b1.u[jj] = Bs[q*4 + jj][wn + 16 + mr];
        }
        acc[0][0] = __builtin_amdgcn_mfma_f32_16x16x32_bf16(af0, b0.v, acc[0][0], 0, 0, 0);
        acc[0][1] = __builtin_amdgcn_mfma_f32_16x16x32_bf16(af0, b1.v, acc[0][1], 0, 0, 0);
        acc[1][0] = __builtin_amdgcn_mfma_f32_16x16x32_bf16(af1, b0.v, acc[1][0], 0, 0, 0);
        acc[1][1] = __builtin_amdgcn_mfma_f32_16x16x32_bf16(af1, b1.v, acc[1][1], 0, 0, 0);
        __syncthreads();
    }
    const bool addb = (blockIdx.z == 0);
    #pragma unroll
    for (int si = 0; si < 2; ++si) {
        #pragma unroll
        for (int sj = 0; sj < 2; ++sj) {
            int n = n0 + wn + sj*16 + mr;
            float bv = 0.f;
            if constexpr (EPI != EPI_NONE) bv = bias[n];
            #pragma unroll
            for (int r = 0; r < 4; ++r) {
                int m = m0 + wm + si*16 + q*4 + r;
                if (m < M) {
                    if constexpr (EPI == EPI_ATOMIC) {
                        float v = acc[si][sj][r] + (addb ? bv : 0.f);
                        atomicAdd(&((float*)Cv)[(size_t)m * N + n], v);
                    } else {
                        float v = acc[si][sj][r] + bv;
                        if constexpr (EPI == EPI_BIAS_GELU)
                            v = 0.5f * v * (1.f + erff(v * 0.70710678118654752f));
                        if constexpr (EPI == EPI_BIAS_RES)
                            v += Rres[(size_t)m * N + n];
                        if constexpr (EPI == EPI_BIAS || EPI == EPI_BIAS_GELU)
                            ((__bf16*)Cv)[(size_t)m * N + n] = (__bf16)v;
                        else
                            ((float*)Cv)[(size_t)m * N + n] = v;
                    }
                }
            }
        }
    }
}

// ================= MFMA fused attention (f32 qkv input, bias pre-added) =================
__global__ __launch_bounds__(256) void attn_kernel(
    const float* __restrict__ qkv, const float* __restrict__ tab,
    const int* __restrict__ rpe, __bf16* __restrict__ y2)
{
    __shared__ __bf16 Vt[64][232];        // V^T: [d][key]
    __shared__ __bf16 Pl[4][16][232];     // per-wave P tile [qrow][key]
    int blk = blockIdx.x;                 // b*32 + h*4 + qg
    int qg = blk & 3, h = (blk >> 2) & 7, b = blk >> 5;
    int tid = threadIdx.x;

    // ---- stage V transposed ----
    for (int i = tid; i < 196*8; i += 256) {
        int key = i >> 3, seg = i & 7;
        const float* vp = qkv + ((size_t)(b*Np + key))*1536 + 1024 + h*64 + seg*8;
        float4 v0 = *(const float4*)vp, v1 = *(const float4*)(vp + 4);
        Vt[seg*8+0][key] = (__bf16)v0.x; Vt[seg*8+1][key] = (__bf16)v0.y;
        Vt[seg*8+2][key] = (__bf16)v0.z; Vt[seg*8+3][key] = (__bf16)v0.w;
        Vt[seg*8+4][key] = (__bf16)v1.x; Vt[seg*8+5][key] = (__bf16)v1.y;
        Vt[seg*8+6][key] = (__bf16)v1.z; Vt[seg*8+7][key] = (__bf16)v1.w;
    }
    {
        int d0 = tid >> 2, cs = tid & 3;
        #pragma unroll
        for (int j = 0; j < 9; ++j) Vt[d0][196 + cs*9 + j] = (__bf16)0.f;
    }
    __syncthreads();

    int lane = tid & 63, wave = tid >> 6;
    int T = qg + 4*wave;
    if (T > 12) return;
    int q = lane >> 4, mr = lane & 15;

    if (lane < 36) {
        #pragma unroll
        for (int r = 0; r < 16; ++r) Pl[wave][r][196 + lane] = (__bf16)0.f;
    }

    // ---- Q fragments ----
    int qtok = b*Np + min(T*16 + mr, 195);
    const float* qp = qkv + (size_t)qtok*1536 + h*64 + q*8;
    bf16x8 aq0 = ld8f(qp);
    bf16x8 aq1 = ld8f(qp + 32);

    // ---- S = Q @ K^T ----
    f32x4 sacc[13];
    #pragma unroll
    for (int nt = 0; nt < 13; ++nt) {
        int ktok = b*Np + min(nt*16 + mr, 195);
        const float* kp = qkv + (size_t)ktok*1536 + 512 + h*64 + q*8;
        bf16x8 bk0 = ld8f(kp);
        bf16x8 bk1 = ld8f(kp + 32);
        f32x4 z = (f32x4){0.f, 0.f, 0.f, 0.f};
        z = __builtin_amdgcn_mfma_f32_16x16x32_bf16(aq0, bk0, z, 0, 0, 0);
        sacc[nt] = __builtin_amdgcn_mfma_f32_16x16x32_bf16(aq1, bk1, z, 0, 0, 0);
    }

    // ---- bias + softmax per row ----
    #pragma unroll
    for (int r = 0; r < 4; ++r) {
        int qi = T*16 + q*4 + r;
        const int* rrow = rpe + (size_t)min(qi, 195) * 196;
        float vals[13];
        #pragma unroll
        for (int nt = 0; nt < 13; ++nt) {
            int col = nt*16 + mr;
            float bv = tab[rrow[min(col, 195)]*8 + h];
            float v = sacc[nt][r] * 0.125f + bv;
            vals[nt] = (col < 196) ? v : -3.0e38f;
        }
        float m = vals[0];
        #pragma unroll
        for (int nt = 1; nt < 13; ++nt) m = fmaxf(m, vals[nt]);
        #pragma unroll
        for (int o = 8; o > 0; o >>= 1) m = fmaxf(m, __shfl_xor(m, o, 64));
        float s = 0.f, p[13];
        #pragma unroll
        for (int nt = 0; nt < 13; ++nt) { p[nt] = __expf(vals[nt] - m); s += p[nt]; }
        #pragma unroll
        for (int o = 8; o > 0; o >>= 1) s += __shfl_xor(s, o, 64);
        float inv = 1.f / s;
        #pragma unroll
        for (int nt = 0; nt < 13; ++nt)
            Pl[wave][q*4 + r][nt*16 + mr] = (__bf16)(p[nt] * inv);
    }

    // ---- O = P @ V ----
    f32x4 oacc[4];
    #pragma unroll
    for (int nt = 0; nt < 4; ++nt) oacc[nt] = (f32x4){0.f, 0.f, 0.f, 0.f};
    #pragma unroll
    for (int ks = 0; ks < 7; ++ks) {
        bf16x8 ap = *(const bf16x8*)&Pl[wave][mr][ks*32 + q*8];
        #pragma unroll
        for (int nt = 0; nt < 4; ++nt) {
            bf16x8 bv = *(const bf16x8*)&Vt[nt*16 + mr][ks*32 + q*8];
            oacc[nt] = __builtin_amdgcn_mfma_f32_16x16x32_bf16(ap, bv, oacc[nt], 0, 0, 0);
        }
    }

    #pragma unroll
    for (int nt = 0; nt < 4; ++nt) {
        #pragma unroll
        for (int r = 0; r < 4; ++r) {
            int qi = T*16 + q*4 + r;
            if (qi < 196)
                y2[((size_t)(b*Np + qi))*512 + h*64 + nt*16 + mr] = (__bf16)oacc[nt][r];
        }
    }
}

// ================= ape add =================
__global__ __launch_bounds__(256) void add_ape_kernel(float* __restrict__ x,
                                                      const float* __restrict__ ape)
{
    int i = blockIdx.x * 256 + threadIdx.x;
    if (i < 1568*512) x[i] += ape[i % (Np*512)];
}

// ================= launcher =================
extern "C" void kernel_launch(void* const* d_in, const int* in_sizes, int n_in,
                              void* d_out, int out_size, void* d_ws, size_t ws_size,
                              hipStream_t stream)
{
    typedef const float* fp;
    fp image  = (fp)d_in[0];
    fp conv_w = (fp)d_in[1];  fp conv_b = (fp)d_in[2];
    fp pn_g   = (fp)d_in[3];  fp pn_b   = (fp)d_in[4];
    fp s1_ng  = (fp)d_in[5];  fp s1_nb  = (fp)d_in[6];
    fp s1_w1  = (fp)d_in[7];  fp s1_b1  = (fp)d_in[8];
    fp s1_w2  = (fp)d_in[9];  fp s1_b2  = (fp)d_in[10];
    fp s2_ng  = (fp)d_in[11]; fp s2_nb  = (fp)d_in[12];
    fp s2_w1  = (fp)d_in[13]; fp s2_b1  = (fp)d_in[14];
    fp s2_w2  = (fp)d_in[15]; fp s2_b2  = (fp)d_in[16];
    fp pm1_ng = (fp)d_in[17]; fp pm1_nb = (fp)d_in[18]; fp pm1_rw = (fp)d_in[19];
    fp pm2_ng = (fp)d_in[20]; fp pm2_nb = (fp)d_in[21]; fp pm2_rw = (fp)d_in[22];
    fp ape    = (fp)d_in[23];
    fp n1g    = (fp)d_in[24]; fp n1b    = (fp)d_in[25];
    fp qkvw   = (fp)d_in[26]; fp qkvb   = (fp)d_in[27];
    fp tab    = (fp)d_in[28];
    fp projw  = (fp)d_in[29]; fp projb  = (fp)d_in[30];
    fp n2g    = (fp)d_in[31]; fp n2b    = (fp)d_in[32];
    fp w1     = (fp)d_in[33]; fp b1     = (fp)d_in[34];
    fp w2     = (fp)d_in[35]; fp b2     = (fp)d_in[36];
    const int* rpe = (const int*)d_in[37];

    float*  X  = (float*)d_ws;                // 3,211,264 f32 residual
    __bf16* H  = (__bf16*)(X + 3211264);      // 9,633,792 bf16 hidden (stage mlps / mlp1)
    float*  Hf = (float*)H;                   // aliases H: 2,408,448 f32 qkv (disjoint lifetime)
    __bf16* Y  = H + 9633792;                 // 3,211,264 bf16 LN out / attn out

    conv_ln_kernel<<<Bb*56*56, 128, 0, stream>>>(image, conv_w, conv_b, pn_g, pn_b, X);

    for (int t = 0; t < 3; ++t) {
        ln_kernel<<<25088/4, 256, 0, stream>>>(X, s1_ng + t*128, s1_nb + t*128, Y, 25088, 128);
        gemm_kernel<EPI_BIAS_GELU><<<dim3(384/64, 25088/64), 256, 0, stream>>>(
            Y, s1_w1 + (size_t)t*128*384, s1_b1 + t*384, nullptr, H, 25088, 384, 128, 128);
        gemm_kernel<EPI_BIAS_RES><<<dim3(128/64, 25088/64), 256, 0, stream>>>(
            H, s1_w2 + (size_t)t*384*128, s1_b2 + t*128, X, X, 25088, 128, 384, 384);
    }
    merge1_ln_kernel<<<6272/4, 256, 0, stream>>>(X, pm1_ng, pm1_nb, Y);
    gemm_kernel<EPI_NONE><<<dim3(256/64, 6272/64), 256, 0, stream>>>(
        Y, pm1_rw, nullptr, nullptr, X, 6272, 256, 512, 512);
    for (int t = 0; t < 3; ++t) {
        ln_kernel<<<6272/4, 256, 0, stream>>>(X, s2_ng + t*256, s2_nb + t*256, Y, 6272, 256);
        gemm_kernel<EPI_BIAS_GELU><<<dim3(768/64, 6272/64), 256, 0, stream>>>(
            Y, s2_w1 + (size_t)t*256*768, s2_b1 + t*768, nullptr, H, 6272, 768, 256, 256);
        gemm_kernel<EPI_BIAS_RES><<<dim3(256/64, 6272/64), 256, 0, stream>>>(
            H, s2_w2 + (size_t)t*768*256, s2_b2 + t*256, X, X, 6272, 256, 768, 768);
    }
    merge2_ln_kernel<<<1568/4, 256, 0, stream>>>(X, pm2_ng, pm2_nb, Y);
    gemm_kernel<EPI_NONE><<<dim3(512/64, (1568+63)/64), 256, 0, stream>>>(
        Y, pm2_rw, nullptr, nullptr, X, 1568, 512, 1024, 1024);
    add_ape_kernel<<<(1568*512+255)/256, 256, 0, stream>>>(X, ape);

    const int MT = (1568 + 63) / 64;   // 25
    for (int l = 0; l < DEPTH; ++l) {
        hipMemsetAsync(Hf, 0, (size_t)1568*1536*sizeof(float), stream);
        ln_kernel<<<392, 256, 0, stream>>>(X, n1g + l*EMB, n1b + l*EMB, Y, 1568, EMB);
        // qkv: split-K x2, atomic into zeroed Hf (bias added by z==0)
        gemm_kernel<EPI_ATOMIC><<<dim3(1536/64, MT, 2), 256, 0, stream>>>(
            Y, qkvw + (size_t)l*EMB*1536, qkvb + (size_t)l*1536, nullptr, Hf, 1568, 1536, EMB, 256);
        attn_kernel<<<256, 256, 0, stream>>>(Hf, tab + (size_t)l*RPEL*HEADS, rpe, Y);
        // proj: split-K x4, atomic directly onto residual X (res-add free)
        gemm_kernel<EPI_ATOMIC><<<dim3(512/64, MT, 4), 256, 0, stream>>>(
            Y, projw + (size_t)l*EMB*EMB, projb + (size_t)l*EMB, nullptr, X, 1568, EMB, EMB, 128);
        ln_kernel<<<392, 256, 0, stream>>>(X, n2g + l*EMB, n2b + l*EMB, Y, 1568, EMB);
        // mlp1: no split (GELU epilogue must see full sum), 800 blocks
        gemm_kernel<EPI_BIAS_GELU><<<dim3(2048/64, MT), 256, 0, stream>>>(
            Y, w1 + (size_t)l*EMB*2048, b1 + (size_t)l*2048, nullptr, H, 1568, 2048, EMB, EMB);
        // mlp2: split-K x8, atomic onto residual X
        gemm_kernel<EPI_ATOMIC><<<dim3(512/64, MT, 8), 256, 0, stream>>>(
            H, w2 + (size_t)l*2048*EMB, b2 + (size_t)l*EMB, nullptr, X, 1568, EMB, 2048, 256);
    }
    hipMemcpyAsync(d_out, X, (size_t)1568*512*sizeof(float), hipMemcpyDeviceToDevice, stream);
}